// Round 4
// baseline (500.672 us; speedup 1.0000x reference)
//
#include <hip/hip_runtime.h>
#include <math.h>

typedef unsigned short u16;
typedef unsigned int   u32;

#define B_   16
#define C_   256
#define HW_  1024
#define N_   16384      // B*H*W rows
#define NE_  8192       // codebook entries
#define K_   256        // feature dim
#define NSPLIT 8
#define CPS  1024       // codes per split
#define NZQ  4194304    // B*C*H*W

typedef __bf16 bf16x8 __attribute__((ext_vector_type(8)));
typedef float  f32x16 __attribute__((ext_vector_type(16)));

// output layout: [0, NZQ) = z_q (B,C,H,W); [NZQ] = loss; [NZQ+1, NZQ+1+N_) = indices (as float)

__device__ __forceinline__ void bf16split(float x, u16& h, u16& l) {
    u32 u = __float_as_uint(x);
    u32 r = (u + 0x7fffu + ((u >> 16) & 1u)) >> 16;
    h = (u16)r;
    float hf = __uint_as_float(r << 16);
    float lo = x - hf;
    u32 u2 = __float_as_uint(lo);
    u32 r2 = (u2 + 0x7fffu + ((u2 >> 16) & 1u)) >> 16;
    l = (u16)r2;
}

// ---------------------------------------------------------------------------
// A: transpose z (B,C,HW) -> z_flat [N_, K_] fp32 + bf16 hi/lo splits
__global__ void k_transpose_z(const float* __restrict__ z, float* __restrict__ zf,
                              u16* __restrict__ zh, u16* __restrict__ zl) {
    __shared__ float tile[32][33];
    int b   = blockIdx.z;
    int hw0 = blockIdx.x * 32;
    int c0  = blockIdx.y * 32;
    int tx = threadIdx.x;   // 0..31
    int ty = threadIdx.y;   // 0..7
    #pragma unroll
    for (int i = 0; i < 4; ++i) {
        int c = c0 + ty + i * 8;
        tile[ty + i * 8][tx] = z[((size_t)b * C_ + c) * HW_ + hw0 + tx];
    }
    __syncthreads();
    #pragma unroll
    for (int i = 0; i < 4; ++i) {
        int hw = hw0 + ty + i * 8;
        size_t o = ((size_t)b * HW_ + hw) * C_ + c0 + tx;
        float v = tile[tx][ty + i * 8];
        zf[o] = v;
        u16 h, l;
        bf16split(v, h, l);
        zh[o] = h; zl[o] = l;
    }
}

// ---------------------------------------------------------------------------
// B: codebook GEMM: cb[n][c] = sum_d frozen[n][d] * w[c][d]; also bf16 hi/lo
__global__ __launch_bounds__(256) void k_codebook_gemm(
        const float* __restrict__ f, const float* __restrict__ w,
        float* __restrict__ cb, u16* __restrict__ cbh, u16* __restrict__ cbl) {
    __shared__ float Fs[16][68];
    __shared__ float Ws[16][68];
    int n0 = blockIdx.x * 64;
    int c0 = blockIdx.y * 64;
    int tid = threadIdx.x;
    int tx = tid & 15, ty = tid >> 4;
    int nl = tid >> 2;            // 0..63
    int kq = (tid & 3) * 4;       // 0,4,8,12
    float acc[4][4] = {};
    for (int kb = 0; kb < K_; kb += 16) {
        float4 fv = *(const float4*)&f[(size_t)(n0 + nl) * K_ + kb + kq];
        float4 wv = *(const float4*)&w[(size_t)(c0 + nl) * K_ + kb + kq];
        __syncthreads();
        Fs[kq + 0][nl] = fv.x; Fs[kq + 1][nl] = fv.y; Fs[kq + 2][nl] = fv.z; Fs[kq + 3][nl] = fv.w;
        Ws[kq + 0][nl] = wv.x; Ws[kq + 1][nl] = wv.y; Ws[kq + 2][nl] = wv.z; Ws[kq + 3][nl] = wv.w;
        __syncthreads();
        #pragma unroll
        for (int k = 0; k < 16; ++k) {
            float4 a = *(float4*)&Fs[k][ty * 4];
            float4 b = *(float4*)&Ws[k][tx * 4];
            float av[4] = {a.x, a.y, a.z, a.w};
            float bv[4] = {b.x, b.y, b.z, b.w};
            #pragma unroll
            for (int i = 0; i < 4; ++i)
                #pragma unroll
                for (int j = 0; j < 4; ++j)
                    acc[i][j] += av[i] * bv[j];
        }
    }
    #pragma unroll
    for (int i = 0; i < 4; ++i) {
        size_t o = (size_t)(n0 + ty * 4 + i) * K_ + c0 + tx * 4;
        *(float4*)&cb[o] = make_float4(acc[i][0], acc[i][1], acc[i][2], acc[i][3]);
        u16 h[4], l[4];
        #pragma unroll
        for (int j = 0; j < 4; ++j) bf16split(acc[i][j], h[j], l[j]);
        *(ushort4*)&cbh[o] = make_ushort4(h[0], h[1], h[2], h[3]);
        *(ushort4*)&cbl[o] = make_ushort4(l[0], l[1], l[2], l[3]);
    }
}

// ---------------------------------------------------------------------------
// B2: c2[n] = ||cb[n]||^2
__global__ void k_c2(const float* __restrict__ cb, float* __restrict__ c2) {
    int row  = blockIdx.x * 4 + (threadIdx.x >> 6);
    int lane = threadIdx.x & 63;
    float4 v = *(const float4*)&cb[(size_t)row * K_ + lane * 4];
    float s = v.x * v.x + v.y * v.y + v.z * v.z + v.w * v.w;
    #pragma unroll
    for (int off = 32; off; off >>= 1) s += __shfl_down(s, off, 64);
    if (lane == 0) c2[row] = s;
}

// ---------------------------------------------------------------------------
// C: MFMA split-bf16 distance scan. score = ||c||^2 - 2 z.c
// Block: 128 z-rows x one split (1024 codes), tiles of 128 codes.
// Waves 2x2: wm = code half (64), wn = z half (64). 32x32x16 bf16 MFMA.
// Product order per kb: (cl,zh), (ch,zh), (ch,zl) -> only restage the operand
// that changed (4 of 6 stages per kb instead of 6).
__device__ __forceinline__ void ld_lds16(const void* g, void* l) {
    __builtin_amdgcn_global_load_lds((const __attribute__((address_space(1))) void*)g,
                                     (__attribute__((address_space(3))) void*)l, 16, 0, 0);
}

__global__ __launch_bounds__(256, 4) void k_scan_mfma(
        const u16* __restrict__ zh, const u16* __restrict__ zl,
        const u16* __restrict__ cbh, const u16* __restrict__ cbl,
        const float* __restrict__ c2, int* __restrict__ t2i) {
    __shared__ u16 As[8192];        // 128 codes x 64 k, xor-swizzled 16B units
    __shared__ u16 Bs[8192];        // 128 zrows x 64 k
    __shared__ float c2s[128];
    __shared__ float4 mbuf[256];

    int r0    = blockIdx.x * 128;
    int split = blockIdx.y;
    int tid  = threadIdx.x;
    int wave = tid >> 6, lane = tid & 63;
    int wm = wave >> 1, wn = wave & 1;
    int l31 = lane & 31, q = lane >> 5;

    // staging address precompute (same for all rounds)
    int S0 = wave * 64 + lane;      // it=0 slot
    // per it: S = (it*4+wave)*64 + lane

    // running top-2 per lane per j
    float rs1[2] = {1e30f, 1e30f}, rs2[2] = {1e30f, 1e30f};
    int   ri1[2] = {0, 0},         ri2[2] = {0, 0};

    for (int ct = 0; ct < CPS / 128; ++ct) {
        int code0 = split * CPS + ct * 128;
        f32x16 acc00 = {}, acc01 = {}, acc10 = {}, acc11 = {};
        for (int kb = 0; kb < K_; kb += 64) {
            #pragma unroll
            for (int p = 0; p < 3; ++p) {
                const u16* Ap = (p == 0) ? cbl : cbh;
                const u16* Bp = (p == 2) ? zl  : zh;
                const u16* Abase = Ap + (size_t)code0 * K_ + kb;
                const u16* Bbase = Bp + (size_t)r0 * K_ + kb;
                __syncthreads();
                #pragma unroll
                for (int it = 0; it < 4; ++it) {
                    int S = (it * 4 + wave) * 64 + lane;
                    int row = S >> 3, u = S & 7;
                    int k8 = (u ^ (row & 7)) * 8;
                    if (p != 2)   // A changes on p=0 (cl) and p=1 (ch)
                        ld_lds16(Abase + (size_t)row * K_ + k8, &As[(size_t)(it * 4 + wave) * 512]);
                    if (p != 1)   // B changes on p=0 (zh) and p=2 (zl)
                        ld_lds16(Bbase + (size_t)row * K_ + k8, &Bs[(size_t)(it * 4 + wave) * 512]);
                }
                if (p == 0 && kb == 0 && tid < 128) c2s[tid] = c2[code0 + tid];
                __syncthreads();
                #pragma unroll
                for (int ks = 0; ks < 4; ++ks) {
                    bf16x8 af[2], bf[2];
                    #pragma unroll
                    for (int i = 0; i < 2; ++i) {
                        int rowa = wm * 64 + i * 32 + l31;
                        af[i] = *(const bf16x8*)&As[(rowa * 8 + ((ks * 2 + q) ^ (rowa & 7))) * 8];
                        int rowb = wn * 64 + i * 32 + l31;
                        bf[i] = *(const bf16x8*)&Bs[(rowb * 8 + ((ks * 2 + q) ^ (rowb & 7))) * 8];
                    }
                    acc00 = __builtin_amdgcn_mfma_f32_32x32x16_bf16(af[0], bf[0], acc00, 0, 0, 0);
                    acc01 = __builtin_amdgcn_mfma_f32_32x32x16_bf16(af[0], bf[1], acc01, 0, 0, 0);
                    acc10 = __builtin_amdgcn_mfma_f32_32x32x16_bf16(af[1], bf[0], acc10, 0, 0, 0);
                    acc11 = __builtin_amdgcn_mfma_f32_32x32x16_bf16(af[1], bf[1], acc11, 0, 0, 0);
                }
            }
        }
        // epilogue: scores for this 128-code tile, insert into running top-2
        float c2r[2][16];
        #pragma unroll
        for (int i = 0; i < 2; ++i)
            #pragma unroll
            for (int h = 0; h < 4; ++h) {
                float4 v = *(float4*)&c2s[wm * 64 + i * 32 + 4 * q + 8 * h];
                c2r[i][h * 4 + 0] = v.x; c2r[i][h * 4 + 1] = v.y;
                c2r[i][h * 4 + 2] = v.z; c2r[i][h * 4 + 3] = v.w;
            }
        const f32x16* accp[2][2] = {{&acc00, &acc01}, {&acc10, &acc11}};
        #pragma unroll
        for (int j = 0; j < 2; ++j) {
            #pragma unroll
            for (int i = 0; i < 2; ++i) {
                const f32x16& a = *accp[i][j];
                #pragma unroll
                for (int r = 0; r < 16; ++r) {
                    float s = c2r[i][r] - 2.0f * a[r];
                    int idx = code0 + wm * 64 + i * 32 + 4 * q + (r & 3) + 8 * (r >> 2);
                    if (s < rs1[j])      { rs2[j] = rs1[j]; ri2[j] = ri1[j]; rs1[j] = s; ri1[j] = idx; }
                    else if (s < rs2[j]) { rs2[j] = s; ri2[j] = idx; }
                }
            }
        }
    }
    // merge q-halves (lanes l <-> l^32)
    #pragma unroll
    for (int j = 0; j < 2; ++j) {
        float os1 = __shfl_xor(rs1[j], 32, 64);
        int   oi1 = __shfl_xor(ri1[j], 32, 64);
        float os2 = __shfl_xor(rs2[j], 32, 64);
        int   oi2 = __shfl_xor(ri2[j], 32, 64);
        if (os1 < rs1[j])      { rs2[j] = rs1[j]; ri2[j] = ri1[j]; rs1[j] = os1; ri1[j] = oi1; }
        else if (os1 < rs2[j]) { rs2[j] = os1; ri2[j] = oi1; }
        if (os2 < rs1[j])      { rs2[j] = rs1[j]; ri2[j] = ri1[j]; rs1[j] = os2; ri1[j] = oi2; }
        else if (os2 < rs2[j]) { rs2[j] = os2; ri2[j] = oi2; }
    }
    __syncthreads();
    if (q == 0) {
        #pragma unroll
        for (int j = 0; j < 2; ++j)
            mbuf[((wm * 2 + wn) * 2 + j) * 32 + l31] =
                make_float4(rs1[j], __int_as_float(ri1[j]), rs2[j], __int_as_float(ri2[j]));
    }
    __syncthreads();
    if (tid < 128) {
        int wn_ = tid >> 6, j_ = (tid >> 5) & 1, l5 = tid & 31;
        float4 e0 = mbuf[((0 * 2 + wn_) * 2 + j_) * 32 + l5];
        float4 e1 = mbuf[((1 * 2 + wn_) * 2 + j_) * 32 + l5];
        float bs1 = e0.x; int bi1 = __float_as_int(e0.y);
        float bs2 = e0.z; int bi2 = __float_as_int(e0.w);
        float cs[2] = {e1.x, e1.z};
        int   ci[2] = {__float_as_int(e1.y), __float_as_int(e1.w)};
        #pragma unroll
        for (int t = 0; t < 2; ++t) {
            if (cs[t] < bs1)      { bs2 = bs1; bi2 = bi1; bs1 = cs[t]; bi1 = ci[t]; }
            else if (cs[t] < bs2) { bs2 = cs[t]; bi2 = ci[t]; }
        }
        int n = r0 + tid;
        size_t o = ((size_t)split * N_ + n) * 2;
        t2i[o] = bi1; t2i[o + 1] = bi2;
    }
}

// ---------------------------------------------------------------------------
// D: fp64 rescore of 16 candidates/row -> final index; gather z_q; loss partials;
//    write z_q directly in (B,C,H,W) layout via LDS transpose.
__global__ __launch_bounds__(256) void k_finalize(
        const float* __restrict__ zf, const float* __restrict__ cb,
        const int* __restrict__ t2i,
        float* __restrict__ out, float* __restrict__ partials) {
    __shared__ double sc[16];
    __shared__ int    li[16];
    __shared__ int    bidx[16];
    __shared__ float  wsum[4];
    __shared__ float  tile[16][260];
    int n0 = blockIdx.x * 16;
    int tid  = threadIdx.x;
    int cand = tid >> 4;          // 0..15
    int lane = tid & 15;
    int split = cand >> 1, which = cand & 1;

    for (int l = 0; l < 16; ++l) {
        int n = n0 + l;
        int ci = t2i[((size_t)split * N_ + n) * 2 + which];
        double acc = 0.0, ccs = 0.0;
        #pragma unroll
        for (int j = 0; j < 16; ++j) {
            int c = lane + 16 * j;
            double zc = (double)zf[(size_t)n * K_ + c];
            double bc = (double)cb[(size_t)ci * K_ + c];
            acc += zc * bc;
            ccs += bc * bc;
        }
        #pragma unroll
        for (int off = 8; off; off >>= 1) {
            acc += __shfl_down(acc, off, 16);
            ccs += __shfl_down(ccs, off, 16);
        }
        if (lane == 0) { sc[cand] = ccs - 2.0 * acc; li[cand] = ci; }
        __syncthreads();
        if (tid == 0) {
            double bs = sc[0]; int bi = li[0];
            for (int t = 1; t < 16; ++t)
                if (sc[t] < bs || (sc[t] == bs && li[t] < bi)) { bs = sc[t]; bi = li[t]; }
            bidx[l] = bi;
            out[(size_t)NZQ + 1 + n] = (float)bi;   // indices output
        }
        __syncthreads();
    }
    // phase 2: gather + squared-error partial + stage for transposed write
    float accl = 0.f;
    for (int l = 0; l < 16; ++l) {
        int n = n0 + l;
        int bi = bidx[l];
        float zq = cb[(size_t)bi * K_ + tid];
        float d  = zf[(size_t)n * K_ + tid] - zq;
        accl += d * d;
        tile[l][tid] = zq;
    }
    #pragma unroll
    for (int off = 32; off; off >>= 1) accl += __shfl_down(accl, off, 64);
    if ((tid & 63) == 0) wsum[tid >> 6] = accl;
    __syncthreads();
    if (tid == 0) partials[blockIdx.x] = wsum[0] + wsum[1] + wsum[2] + wsum[3];
    // transposed write: out[(b*C + c)*HW + hw0 + l]
    int b = n0 >> 10, hw0 = n0 & 1023;
    #pragma unroll
    for (int g = 0; g < 4; ++g) {
        float4 v = make_float4(tile[g * 4 + 0][tid], tile[g * 4 + 1][tid],
                               tile[g * 4 + 2][tid], tile[g * 4 + 3][tid]);
        *(float4*)&out[((size_t)b * C_ + tid) * HW_ + hw0 + g * 4] = v;
    }
}

// ---------------------------------------------------------------------------
// E: loss = 1.25 * sum(partials) / (N*C)
__global__ void k_loss(const float* __restrict__ partials, float* __restrict__ out) {
    __shared__ double ws4[4];
    int tid = threadIdx.x;
    double s = 0.0;
    for (int i = tid; i < 1024; i += 256) s += (double)partials[i];
    #pragma unroll
    for (int off = 32; off; off >>= 1) s += __shfl_down(s, off, 64);
    if ((tid & 63) == 0) ws4[tid >> 6] = s;
    __syncthreads();
    if (tid == 0) {
        double tot = ws4[0] + ws4[1] + ws4[2] + ws4[3];
        out[NZQ] = (float)(1.25 * tot / (double)NZQ);
    }
}

// ---------------------------------------------------------------------------
extern "C" void kernel_launch(void* const* d_in, const int* in_sizes, int n_in,
                              void* d_out, int out_size, void* d_ws, size_t ws_size,
                              hipStream_t stream) {
    const float* z  = (const float*)d_in[0];
    const float* fc = (const float*)d_in[1];
    const float* wt = (const float*)d_in[2];
    float* out = (float*)d_out;

    float* ws = (float*)d_ws;
    const size_t OFF_ZF   = 0;                               // 4,194,304 f
    const size_t OFF_CB   = OFF_ZF + (size_t)N_ * K_;        // 2,097,152 f
    const size_t OFF_C2   = OFF_CB + (size_t)NE_ * K_;       // 8,192 f
    const size_t OFF_T2I  = OFF_C2 + NE_;                    // 262,144 i
    const size_t OFF_PART = OFF_T2I + (size_t)NSPLIT * N_ * 2; // 1,024 f
    const size_t OFF_ZH   = OFF_PART + 1024;                 // u16 arrays
    const size_t OFF_ZL   = OFF_ZH + (size_t)N_ * K_ / 2;
    const size_t OFF_CBH  = OFF_ZL + (size_t)N_ * K_ / 2;
    const size_t OFF_CBL  = OFF_CBH + (size_t)NE_ * K_ / 2;

    float* zf   = ws + OFF_ZF;
    float* cb   = ws + OFF_CB;
    float* c2   = ws + OFF_C2;
    int*   t2i  = (int*)(ws + OFF_T2I);
    float* part = ws + OFF_PART;
    u16*   zh   = (u16*)(ws + OFF_ZH);
    u16*   zl   = (u16*)(ws + OFF_ZL);
    u16*   cbh  = (u16*)(ws + OFF_CBH);
    u16*   cbl  = (u16*)(ws + OFF_CBL);

    k_transpose_z<<<dim3(HW_ / 32, C_ / 32, B_), dim3(32, 8), 0, stream>>>(z, zf, zh, zl);
    k_codebook_gemm<<<dim3(NE_ / 64, K_ / 64), 256, 0, stream>>>(fc, wt, cb, cbh, cbl);
    k_c2<<<NE_ / 4, 256, 0, stream>>>(cb, c2);
    k_scan_mfma<<<dim3(N_ / 128, NSPLIT), 256, 0, stream>>>(zh, zl, cbh, cbl, c2, t2i);
    k_finalize<<<N_ / 16, 256, 0, stream>>>(zf, cb, t2i, out, part);
    k_loss<<<1, 256, 0, stream>>>(part, out);
}

// Round 5
// 393.295 us; speedup vs baseline: 1.2730x; 1.2730x over previous
//
#include <hip/hip_runtime.h>
#include <math.h>

typedef unsigned short u16;
typedef unsigned int   u32;

#define B_   16
#define C_   256
#define HW_  1024
#define N_   16384      // B*H*W rows
#define NE_  8192       // codebook entries
#define K_   256        // feature dim
#define NSPLIT 8
#define CPS  1024       // codes per split
#define NZQ  4194304    // B*C*H*W

typedef __bf16 bf16x8 __attribute__((ext_vector_type(8)));
typedef float  f32x16 __attribute__((ext_vector_type(16)));

// output layout: [0, NZQ) = z_q (B,C,H,W); [NZQ] = loss; [NZQ+1, NZQ+1+N_) = indices (as float)

__device__ __forceinline__ void bf16split(float x, u16& h, u16& l) {
    u32 u = __float_as_uint(x);
    u32 r = (u + 0x7fffu + ((u >> 16) & 1u)) >> 16;
    h = (u16)r;
    float hf = __uint_as_float(r << 16);
    float lo = x - hf;
    u32 u2 = __float_as_uint(lo);
    u32 r2 = (u2 + 0x7fffu + ((u2 >> 16) & 1u)) >> 16;
    l = (u16)r2;
}

// ---------------------------------------------------------------------------
// A: transpose z (B,C,HW) -> z_flat [N_, K_] fp32 + bf16 hi/lo splits
__global__ void k_transpose_z(const float* __restrict__ z, float* __restrict__ zf,
                              u16* __restrict__ zh, u16* __restrict__ zl) {
    __shared__ float tile[32][33];
    int b   = blockIdx.z;
    int hw0 = blockIdx.x * 32;
    int c0  = blockIdx.y * 32;
    int tx = threadIdx.x;   // 0..31
    int ty = threadIdx.y;   // 0..7
    #pragma unroll
    for (int i = 0; i < 4; ++i) {
        int c = c0 + ty + i * 8;
        tile[ty + i * 8][tx] = z[((size_t)b * C_ + c) * HW_ + hw0 + tx];
    }
    __syncthreads();
    #pragma unroll
    for (int i = 0; i < 4; ++i) {
        int hw = hw0 + ty + i * 8;
        size_t o = ((size_t)b * HW_ + hw) * C_ + c0 + tx;
        float v = tile[tx][ty + i * 8];
        zf[o] = v;
        u16 h, l;
        bf16split(v, h, l);
        zh[o] = h; zl[o] = l;
    }
}

// ---------------------------------------------------------------------------
// B: codebook GEMM: cb[n][c] = sum_d frozen[n][d] * w[c][d]; also bf16 hi/lo
__global__ __launch_bounds__(256) void k_codebook_gemm(
        const float* __restrict__ f, const float* __restrict__ w,
        float* __restrict__ cb, u16* __restrict__ cbh, u16* __restrict__ cbl) {
    __shared__ float Fs[16][68];
    __shared__ float Ws[16][68];
    int n0 = blockIdx.x * 64;
    int c0 = blockIdx.y * 64;
    int tid = threadIdx.x;
    int tx = tid & 15, ty = tid >> 4;
    int nl = tid >> 2;            // 0..63
    int kq = (tid & 3) * 4;       // 0,4,8,12
    float acc[4][4] = {};
    for (int kb = 0; kb < K_; kb += 16) {
        float4 fv = *(const float4*)&f[(size_t)(n0 + nl) * K_ + kb + kq];
        float4 wv = *(const float4*)&w[(size_t)(c0 + nl) * K_ + kb + kq];
        __syncthreads();
        Fs[kq + 0][nl] = fv.x; Fs[kq + 1][nl] = fv.y; Fs[kq + 2][nl] = fv.z; Fs[kq + 3][nl] = fv.w;
        Ws[kq + 0][nl] = wv.x; Ws[kq + 1][nl] = wv.y; Ws[kq + 2][nl] = wv.z; Ws[kq + 3][nl] = wv.w;
        __syncthreads();
        #pragma unroll
        for (int k = 0; k < 16; ++k) {
            float4 a = *(float4*)&Fs[k][ty * 4];
            float4 b = *(float4*)&Ws[k][tx * 4];
            float av[4] = {a.x, a.y, a.z, a.w};
            float bv[4] = {b.x, b.y, b.z, b.w};
            #pragma unroll
            for (int i = 0; i < 4; ++i)
                #pragma unroll
                for (int j = 0; j < 4; ++j)
                    acc[i][j] += av[i] * bv[j];
        }
    }
    #pragma unroll
    for (int i = 0; i < 4; ++i) {
        size_t o = (size_t)(n0 + ty * 4 + i) * K_ + c0 + tx * 4;
        *(float4*)&cb[o] = make_float4(acc[i][0], acc[i][1], acc[i][2], acc[i][3]);
        u16 h[4], l[4];
        #pragma unroll
        for (int j = 0; j < 4; ++j) bf16split(acc[i][j], h[j], l[j]);
        *(ushort4*)&cbh[o] = make_ushort4(h[0], h[1], h[2], h[3]);
        *(ushort4*)&cbl[o] = make_ushort4(l[0], l[1], l[2], l[3]);
    }
}

// ---------------------------------------------------------------------------
// B2: c2[n] = ||cb[n]||^2
__global__ void k_c2(const float* __restrict__ cb, float* __restrict__ c2) {
    int row  = blockIdx.x * 4 + (threadIdx.x >> 6);
    int lane = threadIdx.x & 63;
    float4 v = *(const float4*)&cb[(size_t)row * K_ + lane * 4];
    float s = v.x * v.x + v.y * v.y + v.z * v.z + v.w * v.w;
    #pragma unroll
    for (int off = 32; off; off >>= 1) s += __shfl_down(s, off, 64);
    if (lane == 0) c2[row] = s;
}

// ---------------------------------------------------------------------------
// C: MFMA split-bf16 distance scan. score = ||c||^2 - 2 z.c
// Block: 128 z-rows x one split (1024 codes), tiles of 128 codes.
// Waves 2x2: wm = code half (64), wn = z half (64). 32x32x16 bf16 MFMA.
// Product order per kb: (cl,zh), (ch,zh), (ch,zl) -> only restage the operand
// that changed (4 of 6 stages per kb instead of 6).
// NOTE: __launch_bounds__(256,2) -> VGPR=128 (4 waves/SIMD boundary).
// (256,4) forces the 64-VGPR step and spills the 64-reg accumulator (r4: 436MB
// scratch writes, scan 282->391us). Do not raise the min-waves arg.
__device__ __forceinline__ void ld_lds16(const void* g, void* l) {
    __builtin_amdgcn_global_load_lds((const __attribute__((address_space(1))) void*)g,
                                     (__attribute__((address_space(3))) void*)l, 16, 0, 0);
}

__global__ __launch_bounds__(256, 2) void k_scan_mfma(
        const u16* __restrict__ zh, const u16* __restrict__ zl,
        const u16* __restrict__ cbh, const u16* __restrict__ cbl,
        const float* __restrict__ c2, int* __restrict__ t2i) {
    __shared__ u16 As[8192];        // 128 codes x 64 k, xor-swizzled 16B units
    __shared__ u16 Bs[8192];        // 128 zrows x 64 k
    __shared__ float c2s[128];
    __shared__ float4 mbuf[256];

    int r0    = blockIdx.x * 128;
    int split = blockIdx.y;
    int tid  = threadIdx.x;
    int wave = tid >> 6, lane = tid & 63;
    int wm = wave >> 1, wn = wave & 1;
    int l31 = lane & 31, q = lane >> 5;

    // running top-2 per lane per j
    float rs1[2] = {1e30f, 1e30f}, rs2[2] = {1e30f, 1e30f};
    int   ri1[2] = {0, 0},         ri2[2] = {0, 0};

    for (int ct = 0; ct < CPS / 128; ++ct) {
        int code0 = split * CPS + ct * 128;
        f32x16 acc00 = {}, acc01 = {}, acc10 = {}, acc11 = {};
        for (int kb = 0; kb < K_; kb += 64) {
            #pragma unroll
            for (int p = 0; p < 3; ++p) {
                const u16* Ap = (p == 0) ? cbl : cbh;
                const u16* Bp = (p == 2) ? zl  : zh;
                const u16* Abase = Ap + (size_t)code0 * K_ + kb;
                const u16* Bbase = Bp + (size_t)r0 * K_ + kb;
                __syncthreads();
                #pragma unroll
                for (int it = 0; it < 4; ++it) {
                    int S = (it * 4 + wave) * 64 + lane;
                    int row = S >> 3, u = S & 7;
                    int k8 = (u ^ (row & 7)) * 8;
                    if (p != 2)   // A changes on p=0 (cl) and p=1 (ch)
                        ld_lds16(Abase + (size_t)row * K_ + k8, &As[(size_t)(it * 4 + wave) * 512]);
                    if (p != 1)   // B changes on p=0 (zh) and p=2 (zl)
                        ld_lds16(Bbase + (size_t)row * K_ + k8, &Bs[(size_t)(it * 4 + wave) * 512]);
                }
                if (p == 0 && kb == 0 && tid < 128) c2s[tid] = c2[code0 + tid];
                __syncthreads();
                #pragma unroll
                for (int ks = 0; ks < 4; ++ks) {
                    bf16x8 af[2], bf[2];
                    #pragma unroll
                    for (int i = 0; i < 2; ++i) {
                        int rowa = wm * 64 + i * 32 + l31;
                        af[i] = *(const bf16x8*)&As[(rowa * 8 + ((ks * 2 + q) ^ (rowa & 7))) * 8];
                        int rowb = wn * 64 + i * 32 + l31;
                        bf[i] = *(const bf16x8*)&Bs[(rowb * 8 + ((ks * 2 + q) ^ (rowb & 7))) * 8];
                    }
                    acc00 = __builtin_amdgcn_mfma_f32_32x32x16_bf16(af[0], bf[0], acc00, 0, 0, 0);
                    acc01 = __builtin_amdgcn_mfma_f32_32x32x16_bf16(af[0], bf[1], acc01, 0, 0, 0);
                    acc10 = __builtin_amdgcn_mfma_f32_32x32x16_bf16(af[1], bf[0], acc10, 0, 0, 0);
                    acc11 = __builtin_amdgcn_mfma_f32_32x32x16_bf16(af[1], bf[1], acc11, 0, 0, 0);
                }
            }
        }
        // epilogue: scores for this 128-code tile, insert into running top-2
        float c2r[2][16];
        #pragma unroll
        for (int i = 0; i < 2; ++i)
            #pragma unroll
            for (int h = 0; h < 4; ++h) {
                float4 v = *(float4*)&c2s[wm * 64 + i * 32 + 4 * q + 8 * h];
                c2r[i][h * 4 + 0] = v.x; c2r[i][h * 4 + 1] = v.y;
                c2r[i][h * 4 + 2] = v.z; c2r[i][h * 4 + 3] = v.w;
            }
        const f32x16* accp[2][2] = {{&acc00, &acc01}, {&acc10, &acc11}};
        #pragma unroll
        for (int j = 0; j < 2; ++j) {
            #pragma unroll
            for (int i = 0; i < 2; ++i) {
                const f32x16& a = *accp[i][j];
                #pragma unroll
                for (int r = 0; r < 16; ++r) {
                    float s = c2r[i][r] - 2.0f * a[r];
                    int idx = code0 + wm * 64 + i * 32 + 4 * q + (r & 3) + 8 * (r >> 2);
                    if (s < rs1[j])      { rs2[j] = rs1[j]; ri2[j] = ri1[j]; rs1[j] = s; ri1[j] = idx; }
                    else if (s < rs2[j]) { rs2[j] = s; ri2[j] = idx; }
                }
            }
        }
    }
    // merge q-halves (lanes l <-> l^32)
    #pragma unroll
    for (int j = 0; j < 2; ++j) {
        float os1 = __shfl_xor(rs1[j], 32, 64);
        int   oi1 = __shfl_xor(ri1[j], 32, 64);
        float os2 = __shfl_xor(rs2[j], 32, 64);
        int   oi2 = __shfl_xor(ri2[j], 32, 64);
        if (os1 < rs1[j])      { rs2[j] = rs1[j]; ri2[j] = ri1[j]; rs1[j] = os1; ri1[j] = oi1; }
        else if (os1 < rs2[j]) { rs2[j] = os1; ri2[j] = oi1; }
        if (os2 < rs1[j])      { rs2[j] = rs1[j]; ri2[j] = ri1[j]; rs1[j] = os2; ri1[j] = oi2; }
        else if (os2 < rs2[j]) { rs2[j] = os2; ri2[j] = oi2; }
    }
    __syncthreads();
    if (q == 0) {
        #pragma unroll
        for (int j = 0; j < 2; ++j)
            mbuf[((wm * 2 + wn) * 2 + j) * 32 + l31] =
                make_float4(rs1[j], __int_as_float(ri1[j]), rs2[j], __int_as_float(ri2[j]));
    }
    __syncthreads();
    if (tid < 128) {
        int wn_ = tid >> 6, j_ = (tid >> 5) & 1, l5 = tid & 31;
        float4 e0 = mbuf[((0 * 2 + wn_) * 2 + j_) * 32 + l5];
        float4 e1 = mbuf[((1 * 2 + wn_) * 2 + j_) * 32 + l5];
        float bs1 = e0.x; int bi1 = __float_as_int(e0.y);
        float bs2 = e0.z; int bi2 = __float_as_int(e0.w);
        float cs[2] = {e1.x, e1.z};
        int   ci[2] = {__float_as_int(e1.y), __float_as_int(e1.w)};
        #pragma unroll
        for (int t = 0; t < 2; ++t) {
            if (cs[t] < bs1)      { bs2 = bs1; bi2 = bi1; bs1 = cs[t]; bi1 = ci[t]; }
            else if (cs[t] < bs2) { bs2 = cs[t]; bi2 = ci[t]; }
        }
        int n = r0 + tid;
        size_t o = ((size_t)split * N_ + n) * 2;
        t2i[o] = bi1; t2i[o + 1] = bi2;
    }
}

// ---------------------------------------------------------------------------
// D: fp64 rescore of 16 candidates/row -> final index; gather z_q; loss partials;
//    write z_q directly in (B,C,H,W) layout via LDS transpose.
__global__ __launch_bounds__(256) void k_finalize(
        const float* __restrict__ zf, const float* __restrict__ cb,
        const int* __restrict__ t2i,
        float* __restrict__ out, float* __restrict__ partials) {
    __shared__ double sc[16];
    __shared__ int    li[16];
    __shared__ int    bidx[16];
    __shared__ float  wsum[4];
    __shared__ float  tile[16][260];
    int n0 = blockIdx.x * 16;
    int tid  = threadIdx.x;
    int cand = tid >> 4;          // 0..15
    int lane = tid & 15;
    int split = cand >> 1, which = cand & 1;

    for (int l = 0; l < 16; ++l) {
        int n = n0 + l;
        int ci = t2i[((size_t)split * N_ + n) * 2 + which];
        double acc = 0.0, ccs = 0.0;
        #pragma unroll
        for (int j = 0; j < 16; ++j) {
            int c = lane + 16 * j;
            double zc = (double)zf[(size_t)n * K_ + c];
            double bc = (double)cb[(size_t)ci * K_ + c];
            acc += zc * bc;
            ccs += bc * bc;
        }
        #pragma unroll
        for (int off = 8; off; off >>= 1) {
            acc += __shfl_down(acc, off, 16);
            ccs += __shfl_down(ccs, off, 16);
        }
        if (lane == 0) { sc[cand] = ccs - 2.0 * acc; li[cand] = ci; }
        __syncthreads();
        if (tid == 0) {
            double bs = sc[0]; int bi = li[0];
            for (int t = 1; t < 16; ++t)
                if (sc[t] < bs || (sc[t] == bs && li[t] < bi)) { bs = sc[t]; bi = li[t]; }
            bidx[l] = bi;
            out[(size_t)NZQ + 1 + n] = (float)bi;   // indices output
        }
        __syncthreads();
    }
    // phase 2: gather + squared-error partial + stage for transposed write
    float accl = 0.f;
    for (int l = 0; l < 16; ++l) {
        int n = n0 + l;
        int bi = bidx[l];
        float zq = cb[(size_t)bi * K_ + tid];
        float d  = zf[(size_t)n * K_ + tid] - zq;
        accl += d * d;
        tile[l][tid] = zq;
    }
    #pragma unroll
    for (int off = 32; off; off >>= 1) accl += __shfl_down(accl, off, 64);
    if ((tid & 63) == 0) wsum[tid >> 6] = accl;
    __syncthreads();
    if (tid == 0) partials[blockIdx.x] = wsum[0] + wsum[1] + wsum[2] + wsum[3];
    // transposed write: out[(b*C + c)*HW + hw0 + l]
    int b = n0 >> 10, hw0 = n0 & 1023;
    #pragma unroll
    for (int g = 0; g < 4; ++g) {
        float4 v = make_float4(tile[g * 4 + 0][tid], tile[g * 4 + 1][tid],
                               tile[g * 4 + 2][tid], tile[g * 4 + 3][tid]);
        *(float4*)&out[((size_t)b * C_ + tid) * HW_ + hw0 + g * 4] = v;
    }
}

// ---------------------------------------------------------------------------
// E: loss = 1.25 * sum(partials) / (N*C)
__global__ void k_loss(const float* __restrict__ partials, float* __restrict__ out) {
    __shared__ double ws4[4];
    int tid = threadIdx.x;
    double s = 0.0;
    for (int i = tid; i < 1024; i += 256) s += (double)partials[i];
    #pragma unroll
    for (int off = 32; off; off >>= 1) s += __shfl_down(s, off, 64);
    if ((tid & 63) == 0) ws4[tid >> 6] = s;
    __syncthreads();
    if (tid == 0) {
        double tot = ws4[0] + ws4[1] + ws4[2] + ws4[3];
        out[NZQ] = (float)(1.25 * tot / (double)NZQ);
    }
}

// ---------------------------------------------------------------------------
extern "C" void kernel_launch(void* const* d_in, const int* in_sizes, int n_in,
                              void* d_out, int out_size, void* d_ws, size_t ws_size,
                              hipStream_t stream) {
    const float* z  = (const float*)d_in[0];
    const float* fc = (const float*)d_in[1];
    const float* wt = (const float*)d_in[2];
    float* out = (float*)d_out;

    float* ws = (float*)d_ws;
    const size_t OFF_ZF   = 0;                               // 4,194,304 f
    const size_t OFF_CB   = OFF_ZF + (size_t)N_ * K_;        // 2,097,152 f
    const size_t OFF_C2   = OFF_CB + (size_t)NE_ * K_;       // 8,192 f
    const size_t OFF_T2I  = OFF_C2 + NE_;                    // 262,144 i
    const size_t OFF_PART = OFF_T2I + (size_t)NSPLIT * N_ * 2; // 1,024 f
    const size_t OFF_ZH   = OFF_PART + 1024;                 // u16 arrays
    const size_t OFF_ZL   = OFF_ZH + (size_t)N_ * K_ / 2;
    const size_t OFF_CBH  = OFF_ZL + (size_t)N_ * K_ / 2;
    const size_t OFF_CBL  = OFF_CBH + (size_t)NE_ * K_ / 2;

    float* zf   = ws + OFF_ZF;
    float* cb   = ws + OFF_CB;
    float* c2   = ws + OFF_C2;
    int*   t2i  = (int*)(ws + OFF_T2I);
    float* part = ws + OFF_PART;
    u16*   zh   = (u16*)(ws + OFF_ZH);
    u16*   zl   = (u16*)(ws + OFF_ZL);
    u16*   cbh  = (u16*)(ws + OFF_CBH);
    u16*   cbl  = (u16*)(ws + OFF_CBL);

    k_transpose_z<<<dim3(HW_ / 32, C_ / 32, B_), dim3(32, 8), 0, stream>>>(z, zf, zh, zl);
    k_codebook_gemm<<<dim3(NE_ / 64, K_ / 64), 256, 0, stream>>>(fc, wt, cb, cbh, cbl);
    k_c2<<<NE_ / 4, 256, 0, stream>>>(cb, c2);
    k_scan_mfma<<<dim3(N_ / 128, NSPLIT), 256, 0, stream>>>(zh, zl, cbh, cbl, c2, t2i);
    k_finalize<<<N_ / 16, 256, 0, stream>>>(zf, cb, t2i, out, part);
    k_loss<<<1, 256, 0, stream>>>(part, out);
}

// Round 6
// 347.660 us; speedup vs baseline: 1.4401x; 1.1313x over previous
//
#include <hip/hip_runtime.h>
#include <math.h>

typedef unsigned short u16;
typedef unsigned int   u32;

#define B_   16
#define C_   256
#define HW_  1024
#define N_   16384      // B*H*W rows
#define NE_  8192       // codebook entries
#define K_   256        // feature dim
#define NSPLIT 8
#define CPS  1024       // codes per split
#define NZQ  4194304    // B*C*H*W

typedef __bf16 bf16x8 __attribute__((ext_vector_type(8)));
typedef float  f32x16 __attribute__((ext_vector_type(16)));

// output layout: [0, NZQ) = z_q (B,C,H,W); [NZQ] = loss; [NZQ+1, NZQ+1+N_) = indices (as float)

__device__ __forceinline__ void bf16split(float x, u16& h, u16& l) {
    u32 u = __float_as_uint(x);
    u32 r = (u + 0x7fffu + ((u >> 16) & 1u)) >> 16;
    h = (u16)r;
    float hf = __uint_as_float(r << 16);
    float lo = x - hf;
    u32 u2 = __float_as_uint(lo);
    u32 r2 = (u2 + 0x7fffu + ((u2 >> 16) & 1u)) >> 16;
    l = (u16)r2;
}

// ---------------------------------------------------------------------------
// A: transpose z (B,C,HW) -> z_flat [N_, K_] fp32 + bf16 hi/lo splits
__global__ void k_transpose_z(const float* __restrict__ z, float* __restrict__ zf,
                              u16* __restrict__ zh, u16* __restrict__ zl) {
    __shared__ float tile[32][33];
    int b   = blockIdx.z;
    int hw0 = blockIdx.x * 32;
    int c0  = blockIdx.y * 32;
    int tx = threadIdx.x;   // 0..31
    int ty = threadIdx.y;   // 0..7
    #pragma unroll
    for (int i = 0; i < 4; ++i) {
        int c = c0 + ty + i * 8;
        tile[ty + i * 8][tx] = z[((size_t)b * C_ + c) * HW_ + hw0 + tx];
    }
    __syncthreads();
    #pragma unroll
    for (int i = 0; i < 4; ++i) {
        int hw = hw0 + ty + i * 8;
        size_t o = ((size_t)b * HW_ + hw) * C_ + c0 + tx;
        float v = tile[tx][ty + i * 8];
        zf[o] = v;
        u16 h, l;
        bf16split(v, h, l);
        zh[o] = h; zl[o] = l;
    }
}

// ---------------------------------------------------------------------------
// B: codebook GEMM: cb[n][c] = sum_d frozen[n][d] * w[c][d]; also bf16 hi/lo
__global__ __launch_bounds__(256) void k_codebook_gemm(
        const float* __restrict__ f, const float* __restrict__ w,
        float* __restrict__ cb, u16* __restrict__ cbh, u16* __restrict__ cbl) {
    __shared__ float Fs[16][68];
    __shared__ float Ws[16][68];
    int n0 = blockIdx.x * 64;
    int c0 = blockIdx.y * 64;
    int tid = threadIdx.x;
    int tx = tid & 15, ty = tid >> 4;
    int nl = tid >> 2;            // 0..63
    int kq = (tid & 3) * 4;       // 0,4,8,12
    float acc[4][4] = {};
    for (int kb = 0; kb < K_; kb += 16) {
        float4 fv = *(const float4*)&f[(size_t)(n0 + nl) * K_ + kb + kq];
        float4 wv = *(const float4*)&w[(size_t)(c0 + nl) * K_ + kb + kq];
        __syncthreads();
        Fs[kq + 0][nl] = fv.x; Fs[kq + 1][nl] = fv.y; Fs[kq + 2][nl] = fv.z; Fs[kq + 3][nl] = fv.w;
        Ws[kq + 0][nl] = wv.x; Ws[kq + 1][nl] = wv.y; Ws[kq + 2][nl] = wv.z; Ws[kq + 3][nl] = wv.w;
        __syncthreads();
        #pragma unroll
        for (int k = 0; k < 16; ++k) {
            float4 a = *(float4*)&Fs[k][ty * 4];
            float4 b = *(float4*)&Ws[k][tx * 4];
            float av[4] = {a.x, a.y, a.z, a.w};
            float bv[4] = {b.x, b.y, b.z, b.w};
            #pragma unroll
            for (int i = 0; i < 4; ++i)
                #pragma unroll
                for (int j = 0; j < 4; ++j)
                    acc[i][j] += av[i] * bv[j];
        }
    }
    #pragma unroll
    for (int i = 0; i < 4; ++i) {
        size_t o = (size_t)(n0 + ty * 4 + i) * K_ + c0 + tx * 4;
        *(float4*)&cb[o] = make_float4(acc[i][0], acc[i][1], acc[i][2], acc[i][3]);
        u16 h[4], l[4];
        #pragma unroll
        for (int j = 0; j < 4; ++j) bf16split(acc[i][j], h[j], l[j]);
        *(ushort4*)&cbh[o] = make_ushort4(h[0], h[1], h[2], h[3]);
        *(ushort4*)&cbl[o] = make_ushort4(l[0], l[1], l[2], l[3]);
    }
}

// ---------------------------------------------------------------------------
// B2: c2[n] = ||cb[n]||^2
__global__ void k_c2(const float* __restrict__ cb, float* __restrict__ c2) {
    int row  = blockIdx.x * 4 + (threadIdx.x >> 6);
    int lane = threadIdx.x & 63;
    float4 v = *(const float4*)&cb[(size_t)row * K_ + lane * 4];
    float s = v.x * v.x + v.y * v.y + v.z * v.z + v.w * v.w;
    #pragma unroll
    for (int off = 32; off; off >>= 1) s += __shfl_down(s, off, 64);
    if (lane == 0) c2[row] = s;
}

// ---------------------------------------------------------------------------
// C: MFMA split-bf16 distance scan. score = ||c||^2 - 2 z.c
// All 4 split-operands (cl, ch, zh, zl) resident in LDS simultaneously:
// ONE barrier-pair per kb-chunk (was 3), fragments reused across products
// (8 ds_read_b128 per 12 MFMAs). acc += cl.zh + ch.zh + ch.zl.
// NOTE: __launch_bounds__(256,2) -> ~120 arch VGPR + 64 AGPR = 184 total
// -> 2 waves/SIMD (occupancy is register-bound; (256,4) spills, r4).
__device__ __forceinline__ void ld_lds16(const void* g, void* l) {
    __builtin_amdgcn_global_load_lds((const __attribute__((address_space(1))) void*)g,
                                     (__attribute__((address_space(3))) void*)l, 16, 0, 0);
}

__global__ __launch_bounds__(256, 2) void k_scan_mfma(
        const u16* __restrict__ zh, const u16* __restrict__ zl,
        const u16* __restrict__ cbh, const u16* __restrict__ cbl,
        const float* __restrict__ c2, float* __restrict__ t2s, int* __restrict__ t2i) {
    __shared__ __align__(16) u16 sAl[8192];   // 128 codes x 64 k (cl), xor-swizzled
    __shared__ __align__(16) u16 sAh[8192];   // ch
    __shared__ __align__(16) u16 sBh[8192];   // 128 zrows x 64 k (zh)
    __shared__ __align__(16) u16 sBl[8192];   // zl
    __shared__ float c2s[128];
    __shared__ float4 mbuf[256];

    int r0    = blockIdx.x * 128;
    int split = blockIdx.y;
    int tid  = threadIdx.x;
    int wave = tid >> 6, lane = tid & 63;
    int wm = wave >> 1, wn = wave & 1;
    int l31 = lane & 31, q = lane >> 5;

    // running top-2 per lane per j
    float rs1[2] = {1e30f, 1e30f}, rs2[2] = {1e30f, 1e30f};
    int   ri1[2] = {0, 0},         ri2[2] = {0, 0};

    for (int ct = 0; ct < CPS / 128; ++ct) {
        int code0 = split * CPS + ct * 128;
        f32x16 acc00 = {}, acc01 = {}, acc10 = {}, acc11 = {};
        for (int kb = 0; kb < K_; kb += 64) {
            const u16* Al = cbl + (size_t)code0 * K_ + kb;
            const u16* Ah = cbh + (size_t)code0 * K_ + kb;
            const u16* Bh = zh  + (size_t)r0 * K_ + kb;
            const u16* Bl = zl  + (size_t)r0 * K_ + kb;
            __syncthreads();
            #pragma unroll
            for (int it = 0; it < 4; ++it) {
                int S = (it * 4 + wave) * 64 + lane;
                int row = S >> 3, u = S & 7;
                int k8 = (u ^ (row & 7)) * 8;
                size_t goff = (size_t)row * K_ + k8;
                u32 loff = (u32)(it * 4 + wave) * 512;
                ld_lds16(Al + goff, &sAl[loff]);
                ld_lds16(Ah + goff, &sAh[loff]);
                ld_lds16(Bh + goff, &sBh[loff]);
                ld_lds16(Bl + goff, &sBl[loff]);
            }
            if (kb == 0 && tid < 128) c2s[tid] = c2[code0 + tid];
            __syncthreads();
            #pragma unroll
            for (int ks = 0; ks < 4; ++ks) {
                bf16x8 afl[2], afh[2], bfh[2], bfl[2];
                #pragma unroll
                for (int i = 0; i < 2; ++i) {
                    int rowa = wm * 64 + i * 32 + l31;
                    u32 ao = (u32)(rowa * 8 + ((ks * 2 + q) ^ (rowa & 7))) * 8;
                    afl[i] = *(const bf16x8*)&sAl[ao];
                    afh[i] = *(const bf16x8*)&sAh[ao];
                    int rowb = wn * 64 + i * 32 + l31;
                    u32 bo = (u32)(rowb * 8 + ((ks * 2 + q) ^ (rowb & 7))) * 8;
                    bfh[i] = *(const bf16x8*)&sBh[bo];
                    bfl[i] = *(const bf16x8*)&sBl[bo];
                }
                acc00 = __builtin_amdgcn_mfma_f32_32x32x16_bf16(afl[0], bfh[0], acc00, 0, 0, 0);
                acc01 = __builtin_amdgcn_mfma_f32_32x32x16_bf16(afl[0], bfh[1], acc01, 0, 0, 0);
                acc10 = __builtin_amdgcn_mfma_f32_32x32x16_bf16(afl[1], bfh[0], acc10, 0, 0, 0);
                acc11 = __builtin_amdgcn_mfma_f32_32x32x16_bf16(afl[1], bfh[1], acc11, 0, 0, 0);
                acc00 = __builtin_amdgcn_mfma_f32_32x32x16_bf16(afh[0], bfh[0], acc00, 0, 0, 0);
                acc01 = __builtin_amdgcn_mfma_f32_32x32x16_bf16(afh[0], bfh[1], acc01, 0, 0, 0);
                acc10 = __builtin_amdgcn_mfma_f32_32x32x16_bf16(afh[1], bfh[0], acc10, 0, 0, 0);
                acc11 = __builtin_amdgcn_mfma_f32_32x32x16_bf16(afh[1], bfh[1], acc11, 0, 0, 0);
                acc00 = __builtin_amdgcn_mfma_f32_32x32x16_bf16(afh[0], bfl[0], acc00, 0, 0, 0);
                acc01 = __builtin_amdgcn_mfma_f32_32x32x16_bf16(afh[0], bfl[1], acc01, 0, 0, 0);
                acc10 = __builtin_amdgcn_mfma_f32_32x32x16_bf16(afh[1], bfl[0], acc10, 0, 0, 0);
                acc11 = __builtin_amdgcn_mfma_f32_32x32x16_bf16(afh[1], bfl[1], acc11, 0, 0, 0);
            }
        }
        // epilogue: scores for this 128-code tile, insert into running top-2
        float c2r[2][16];
        #pragma unroll
        for (int i = 0; i < 2; ++i)
            #pragma unroll
            for (int h = 0; h < 4; ++h) {
                float4 v = *(float4*)&c2s[wm * 64 + i * 32 + 4 * q + 8 * h];
                c2r[i][h * 4 + 0] = v.x; c2r[i][h * 4 + 1] = v.y;
                c2r[i][h * 4 + 2] = v.z; c2r[i][h * 4 + 3] = v.w;
            }
        int ibase = code0 + wm * 64 + 4 * q;
        const f32x16* accp[2][2] = {{&acc00, &acc01}, {&acc10, &acc11}};
        #pragma unroll
        for (int j = 0; j < 2; ++j) {
            #pragma unroll
            for (int i = 0; i < 2; ++i) {
                const f32x16& a = *accp[i][j];
                #pragma unroll
                for (int r = 0; r < 16; ++r) {
                    float s = c2r[i][r] - 2.0f * a[r];
                    int idx = ibase + i * 32 + (r & 3) + 8 * (r >> 2);
                    if (s < rs1[j])      { rs2[j] = rs1[j]; ri2[j] = ri1[j]; rs1[j] = s; ri1[j] = idx; }
                    else if (s < rs2[j]) { rs2[j] = s; ri2[j] = idx; }
                }
            }
        }
    }
    // merge q-halves (lanes l <-> l^32)
    #pragma unroll
    for (int j = 0; j < 2; ++j) {
        float os1 = __shfl_xor(rs1[j], 32, 64);
        int   oi1 = __shfl_xor(ri1[j], 32, 64);
        float os2 = __shfl_xor(rs2[j], 32, 64);
        int   oi2 = __shfl_xor(ri2[j], 32, 64);
        if (os1 < rs1[j])      { rs2[j] = rs1[j]; ri2[j] = ri1[j]; rs1[j] = os1; ri1[j] = oi1; }
        else if (os1 < rs2[j]) { rs2[j] = os1; ri2[j] = oi1; }
        if (os2 < rs1[j])      { rs2[j] = rs1[j]; ri2[j] = ri1[j]; rs1[j] = os2; ri1[j] = oi2; }
        else if (os2 < rs2[j]) { rs2[j] = os2; ri2[j] = oi2; }
    }
    __syncthreads();
    if (q == 0) {
        #pragma unroll
        for (int j = 0; j < 2; ++j)
            mbuf[((wm * 2 + wn) * 2 + j) * 32 + l31] =
                make_float4(rs1[j], __int_as_float(ri1[j]), rs2[j], __int_as_float(ri2[j]));
    }
    __syncthreads();
    if (tid < 128) {
        int wn_ = tid >> 6, j_ = (tid >> 5) & 1, l5 = tid & 31;
        float4 e0 = mbuf[((0 * 2 + wn_) * 2 + j_) * 32 + l5];
        float4 e1 = mbuf[((1 * 2 + wn_) * 2 + j_) * 32 + l5];
        float bs1 = e0.x; int bi1 = __float_as_int(e0.y);
        float bs2 = e0.z; int bi2 = __float_as_int(e0.w);
        float cs[2] = {e1.x, e1.z};
        int   ci[2] = {__float_as_int(e1.y), __float_as_int(e1.w)};
        #pragma unroll
        for (int t = 0; t < 2; ++t) {
            if (cs[t] < bs1)      { bs2 = bs1; bi2 = bi1; bs1 = cs[t]; bi1 = ci[t]; }
            else if (cs[t] < bs2) { bs2 = cs[t]; bi2 = ci[t]; }
        }
        int n = r0 + tid;
        size_t o = ((size_t)split * N_ + n) * 2;
        t2s[o] = bs1; t2s[o + 1] = bs2;
        t2i[o] = bi1; t2i[o + 1] = bi2;
    }
}

// ---------------------------------------------------------------------------
// D: prefilter 16 candidates -> top-4 by scan score; fp64 rescore those 4;
//    gather z_q; loss partials; transposed (B,C,H,W) write.
__global__ __launch_bounds__(256) void k_finalize(
        const float* __restrict__ zf, const float* __restrict__ cb,
        const float* __restrict__ t2s, const int* __restrict__ t2i,
        float* __restrict__ out, float* __restrict__ partials) {
    __shared__ int    c4[16][4];
    __shared__ double sc[4];
    __shared__ int    li[4];
    __shared__ int    bidx[16];
    __shared__ float  wsum[4];
    __shared__ float  tile[16][260];
    int n0 = blockIdx.x * 16;
    int tid = threadIdx.x;

    // step 1: per-row top-4 prefilter by stored scan score (error ~2e-5;
    // true argmin evicted only by >=4 flips at that scale -> impossible)
    if (tid < 16) {
        int n = n0 + tid;
        float s4[4] = {1e30f, 1e30f, 1e30f, 1e30f};
        int   i4[4] = {0, 0, 0, 0};
        for (int t = 0; t < 2 * NSPLIT; ++t) {
            int sp = t >> 1, w = t & 1;
            size_t o = ((size_t)sp * N_ + n) * 2 + w;
            float s = t2s[o]; int ci = t2i[o];
            if (s < s4[0])      { s4[3]=s4[2]; i4[3]=i4[2]; s4[2]=s4[1]; i4[2]=i4[1]; s4[1]=s4[0]; i4[1]=i4[0]; s4[0]=s; i4[0]=ci; }
            else if (s < s4[1]) { s4[3]=s4[2]; i4[3]=i4[2]; s4[2]=s4[1]; i4[2]=i4[1]; s4[1]=s; i4[1]=ci; }
            else if (s < s4[2]) { s4[3]=s4[2]; i4[3]=i4[2]; s4[2]=s; i4[2]=ci; }
            else if (s < s4[3]) { s4[3]=s; i4[3]=ci; }
        }
        c4[tid][0] = i4[0]; c4[tid][1] = i4[1]; c4[tid][2] = i4[2]; c4[tid][3] = i4[3];
    }
    __syncthreads();

    // step 2: fp64 rescore of 4 candidates (one wave each), rows serial
    int wv = tid >> 6, lane = tid & 63;
    for (int l = 0; l < 16; ++l) {
        int n = n0 + l;
        int ci = c4[l][wv];
        double acc = 0.0, ccs = 0.0;
        #pragma unroll
        for (int j = 0; j < 4; ++j) {
            int c = lane + 64 * j;
            double zc = (double)zf[(size_t)n * K_ + c];
            double bc = (double)cb[(size_t)ci * K_ + c];
            acc += zc * bc;
            ccs += bc * bc;
        }
        #pragma unroll
        for (int off = 32; off; off >>= 1) {
            acc += __shfl_down(acc, off, 64);
            ccs += __shfl_down(ccs, off, 64);
        }
        if (lane == 0) { sc[wv] = ccs - 2.0 * acc; li[wv] = ci; }
        __syncthreads();
        if (tid == 0) {
            double bs = sc[0]; int bi = li[0];
            for (int t = 1; t < 4; ++t)
                if (sc[t] < bs || (sc[t] == bs && li[t] < bi)) { bs = sc[t]; bi = li[t]; }
            bidx[l] = bi;
            out[(size_t)NZQ + 1 + n] = (float)bi;   // indices output
        }
        __syncthreads();
    }

    // phase 2: gather + squared-error partial + stage for transposed write
    float accl = 0.f;
    for (int l = 0; l < 16; ++l) {
        int n = n0 + l;
        int bi = bidx[l];
        float zq = cb[(size_t)bi * K_ + tid];
        float d  = zf[(size_t)n * K_ + tid] - zq;
        accl += d * d;
        tile[l][tid] = zq;
    }
    #pragma unroll
    for (int off = 32; off; off >>= 1) accl += __shfl_down(accl, off, 64);
    if ((tid & 63) == 0) wsum[tid >> 6] = accl;
    __syncthreads();
    if (tid == 0) partials[blockIdx.x] = wsum[0] + wsum[1] + wsum[2] + wsum[3];
    // transposed write: out[(b*C + c)*HW + hw0 + l]
    int b = n0 >> 10, hw0 = n0 & 1023;
    #pragma unroll
    for (int g = 0; g < 4; ++g) {
        float4 v = make_float4(tile[g * 4 + 0][tid], tile[g * 4 + 1][tid],
                               tile[g * 4 + 2][tid], tile[g * 4 + 3][tid]);
        *(float4*)&out[((size_t)b * C_ + tid) * HW_ + hw0 + g * 4] = v;
    }
}

// ---------------------------------------------------------------------------
// E: loss = 1.25 * sum(partials) / (N*C)
__global__ void k_loss(const float* __restrict__ partials, float* __restrict__ out) {
    __shared__ double ws4[4];
    int tid = threadIdx.x;
    double s = 0.0;
    for (int i = tid; i < 1024; i += 256) s += (double)partials[i];
    #pragma unroll
    for (int off = 32; off; off >>= 1) s += __shfl_down(s, off, 64);
    if ((tid & 63) == 0) ws4[tid >> 6] = s;
    __syncthreads();
    if (tid == 0) {
        double tot = ws4[0] + ws4[1] + ws4[2] + ws4[3];
        out[NZQ] = (float)(1.25 * tot / (double)NZQ);
    }
}

// ---------------------------------------------------------------------------
extern "C" void kernel_launch(void* const* d_in, const int* in_sizes, int n_in,
                              void* d_out, int out_size, void* d_ws, size_t ws_size,
                              hipStream_t stream) {
    const float* z  = (const float*)d_in[0];
    const float* fc = (const float*)d_in[1];
    const float* wt = (const float*)d_in[2];
    float* out = (float*)d_out;

    float* ws = (float*)d_ws;
    const size_t OFF_ZF   = 0;                                   // 4,194,304 f
    const size_t OFF_CB   = OFF_ZF + (size_t)N_ * K_;            // 2,097,152 f
    const size_t OFF_C2   = OFF_CB + (size_t)NE_ * K_;           // 8,192 f
    const size_t OFF_T2S  = OFF_C2 + NE_;                        // 262,144 f
    const size_t OFF_T2I  = OFF_T2S + (size_t)NSPLIT * N_ * 2;   // 262,144 i
    const size_t OFF_PART = OFF_T2I + (size_t)NSPLIT * N_ * 2;   // 1,024 f
    const size_t OFF_ZH   = OFF_PART + 1024;
    const size_t OFF_ZL   = OFF_ZH + (size_t)N_ * K_ / 2;
    const size_t OFF_CBH  = OFF_ZL + (size_t)N_ * K_ / 2;
    const size_t OFF_CBL  = OFF_CBH + (size_t)NE_ * K_ / 2;

    float* zf   = ws + OFF_ZF;
    float* cb   = ws + OFF_CB;
    float* c2   = ws + OFF_C2;
    float* t2s  = ws + OFF_T2S;
    int*   t2i  = (int*)(ws + OFF_T2I);
    float* part = ws + OFF_PART;
    u16*   zh   = (u16*)(ws + OFF_ZH);
    u16*   zl   = (u16*)(ws + OFF_ZL);
    u16*   cbh  = (u16*)(ws + OFF_CBH);
    u16*   cbl  = (u16*)(ws + OFF_CBL);

    k_transpose_z<<<dim3(HW_ / 32, C_ / 32, B_), dim3(32, 8), 0, stream>>>(z, zf, zh, zl);
    k_codebook_gemm<<<dim3(NE_ / 64, K_ / 64), 256, 0, stream>>>(fc, wt, cb, cbh, cbl);
    k_c2<<<NE_ / 4, 256, 0, stream>>>(cb, c2);
    k_scan_mfma<<<dim3(N_ / 128, NSPLIT), 256, 0, stream>>>(zh, zl, cbh, cbl, c2, t2s, t2i);
    k_finalize<<<N_ / 16, 256, 0, stream>>>(zf, cb, t2s, t2i, out, part);
    k_loss<<<1, 256, 0, stream>>>(part, out);
}

// Round 7
// 267.031 us; speedup vs baseline: 1.8750x; 1.3019x over previous
//
#include <hip/hip_runtime.h>
#include <math.h>

typedef unsigned short u16;
typedef unsigned int   u32;

#define B_   16
#define C_   256
#define HW_  1024
#define N_   16384      // B*H*W rows
#define NE_  8192       // codebook entries
#define K_   256        // feature dim
#define NSPLIT 8
#define CPS  1024       // codes per split
#define NZQ  4194304    // B*C*H*W

typedef _Float16 f16x8 __attribute__((ext_vector_type(8)));
typedef float    f32x16 __attribute__((ext_vector_type(16)));

// output layout: [0, NZQ) = z_q (B,C,H,W); [NZQ] = loss; [NZQ+1, NZQ+1+N_) = indices (as float)

__device__ __forceinline__ u16 f2h(float x) {
    union { _Float16 h; u16 u; } c;
    c.h = (_Float16)x;
    return c.u;
}

// ---------------------------------------------------------------------------
// A: transpose z (B,C,HW) -> z_flat [N_, K_] fp32 + fp16
__global__ void k_transpose_z(const float* __restrict__ z, float* __restrict__ zf,
                              u16* __restrict__ zh) {
    __shared__ float tile[32][33];
    int b   = blockIdx.z;
    int hw0 = blockIdx.x * 32;
    int c0  = blockIdx.y * 32;
    int tx = threadIdx.x;   // 0..31
    int ty = threadIdx.y;   // 0..7
    #pragma unroll
    for (int i = 0; i < 4; ++i) {
        int c = c0 + ty + i * 8;
        tile[ty + i * 8][tx] = z[((size_t)b * C_ + c) * HW_ + hw0 + tx];
    }
    __syncthreads();
    #pragma unroll
    for (int i = 0; i < 4; ++i) {
        int hw = hw0 + ty + i * 8;
        size_t o = ((size_t)b * HW_ + hw) * C_ + c0 + tx;
        float v = tile[tx][ty + i * 8];
        zf[o] = v;
        zh[o] = f2h(v);
    }
}

// ---------------------------------------------------------------------------
// B: codebook GEMM: cb[n][c] = sum_d frozen[n][d] * w[c][d]; also fp16 copy
__global__ __launch_bounds__(256) void k_codebook_gemm(
        const float* __restrict__ f, const float* __restrict__ w,
        float* __restrict__ cb, u16* __restrict__ cbh) {
    __shared__ float Fs[16][68];
    __shared__ float Ws[16][68];
    int n0 = blockIdx.x * 64;
    int c0 = blockIdx.y * 64;
    int tid = threadIdx.x;
    int tx = tid & 15, ty = tid >> 4;
    int nl = tid >> 2;            // 0..63
    int kq = (tid & 3) * 4;       // 0,4,8,12
    float acc[4][4] = {};
    for (int kb = 0; kb < K_; kb += 16) {
        float4 fv = *(const float4*)&f[(size_t)(n0 + nl) * K_ + kb + kq];
        float4 wv = *(const float4*)&w[(size_t)(c0 + nl) * K_ + kb + kq];
        __syncthreads();
        Fs[kq + 0][nl] = fv.x; Fs[kq + 1][nl] = fv.y; Fs[kq + 2][nl] = fv.z; Fs[kq + 3][nl] = fv.w;
        Ws[kq + 0][nl] = wv.x; Ws[kq + 1][nl] = wv.y; Ws[kq + 2][nl] = wv.z; Ws[kq + 3][nl] = wv.w;
        __syncthreads();
        #pragma unroll
        for (int k = 0; k < 16; ++k) {
            float4 a = *(float4*)&Fs[k][ty * 4];
            float4 b = *(float4*)&Ws[k][tx * 4];
            float av[4] = {a.x, a.y, a.z, a.w};
            float bv[4] = {b.x, b.y, b.z, b.w};
            #pragma unroll
            for (int i = 0; i < 4; ++i)
                #pragma unroll
                for (int j = 0; j < 4; ++j)
                    acc[i][j] += av[i] * bv[j];
        }
    }
    #pragma unroll
    for (int i = 0; i < 4; ++i) {
        size_t o = (size_t)(n0 + ty * 4 + i) * K_ + c0 + tx * 4;
        *(float4*)&cb[o] = make_float4(acc[i][0], acc[i][1], acc[i][2], acc[i][3]);
        *(ushort4*)&cbh[o] = make_ushort4(f2h(acc[i][0]), f2h(acc[i][1]),
                                          f2h(acc[i][2]), f2h(acc[i][3]));
    }
}

// ---------------------------------------------------------------------------
// B2: c2[n] = ||cb[n]||^2
__global__ void k_c2(const float* __restrict__ cb, float* __restrict__ c2) {
    int row  = blockIdx.x * 4 + (threadIdx.x >> 6);
    int lane = threadIdx.x & 63;
    float4 v = *(const float4*)&cb[(size_t)row * K_ + lane * 4];
    float s = v.x * v.x + v.y * v.y + v.z * v.z + v.w * v.w;
    #pragma unroll
    for (int off = 32; off; off >>= 1) s += __shfl_down(s, off, 64);
    if (lane == 0) c2[row] = s;
}

// ---------------------------------------------------------------------------
// C: single-product fp16 MFMA distance scan. score = ||c||^2 - 2 z.c
// fp16 score error sigma ~4e-4 vs within-split order-stat spacing ~0.8 ->
// true argmin always survives into top-2-per-split; fp64 rescore (top-8)
// makes the final index exact. (r6 was LDS-read-bound at 48 FLOP/B with
// 3-product split-bf16; single product cuts MFMA 3x and LDS/DMA traffic 2x.)
// NOTE: __launch_bounds__(256,2); (256,4) spills the 64-AGPR accumulator (r4).
__device__ __forceinline__ void ld_lds16(const void* g, void* l) {
    __builtin_amdgcn_global_load_lds((const __attribute__((address_space(1))) void*)g,
                                     (__attribute__((address_space(3))) void*)l, 16, 0, 0);
}

__global__ __launch_bounds__(256, 2) void k_scan_mfma(
        const u16* __restrict__ zh, const u16* __restrict__ cbh,
        const float* __restrict__ c2, float* __restrict__ t2s, int* __restrict__ t2i) {
    __shared__ __align__(16) u16 sA[8192];   // 128 codes x 64 k, xor-swizzled 16B units
    __shared__ __align__(16) u16 sB[8192];   // 128 zrows x 64 k
    __shared__ float c2s[128];
    __shared__ float4 mbuf[256];

    int r0    = blockIdx.x * 128;
    int split = blockIdx.y;
    int tid  = threadIdx.x;
    int wave = tid >> 6, lane = tid & 63;
    int wm = wave >> 1, wn = wave & 1;
    int l31 = lane & 31, q = lane >> 5;

    // running top-2 per lane per j
    float rs1[2] = {1e30f, 1e30f}, rs2[2] = {1e30f, 1e30f};
    int   ri1[2] = {0, 0},         ri2[2] = {0, 0};

    for (int ct = 0; ct < CPS / 128; ++ct) {
        int code0 = split * CPS + ct * 128;
        f32x16 acc00 = {}, acc01 = {}, acc10 = {}, acc11 = {};
        for (int kb = 0; kb < K_; kb += 64) {
            const u16* Ab = cbh + (size_t)code0 * K_ + kb;
            const u16* Bb = zh  + (size_t)r0 * K_ + kb;
            __syncthreads();
            #pragma unroll
            for (int it = 0; it < 4; ++it) {
                int S = (it * 4 + wave) * 64 + lane;
                int row = S >> 3, u = S & 7;
                int k8 = (u ^ (row & 7)) * 8;
                size_t goff = (size_t)row * K_ + k8;
                u32 loff = (u32)(it * 4 + wave) * 512;
                ld_lds16(Ab + goff, &sA[loff]);
                ld_lds16(Bb + goff, &sB[loff]);
            }
            if (kb == 0 && tid < 128) c2s[tid] = c2[code0 + tid];
            __syncthreads();
            #pragma unroll
            for (int ks = 0; ks < 4; ++ks) {
                f16x8 af[2], bf[2];
                #pragma unroll
                for (int i = 0; i < 2; ++i) {
                    int rowa = wm * 64 + i * 32 + l31;
                    u32 ao = (u32)(rowa * 8 + ((ks * 2 + q) ^ (rowa & 7))) * 8;
                    af[i] = *(const f16x8*)&sA[ao];
                    int rowb = wn * 64 + i * 32 + l31;
                    u32 bo = (u32)(rowb * 8 + ((ks * 2 + q) ^ (rowb & 7))) * 8;
                    bf[i] = *(const f16x8*)&sB[bo];
                }
                acc00 = __builtin_amdgcn_mfma_f32_32x32x16_f16(af[0], bf[0], acc00, 0, 0, 0);
                acc01 = __builtin_amdgcn_mfma_f32_32x32x16_f16(af[0], bf[1], acc01, 0, 0, 0);
                acc10 = __builtin_amdgcn_mfma_f32_32x32x16_f16(af[1], bf[0], acc10, 0, 0, 0);
                acc11 = __builtin_amdgcn_mfma_f32_32x32x16_f16(af[1], bf[1], acc11, 0, 0, 0);
            }
        }
        // epilogue: scores for this 128-code tile, insert into running top-2
        float c2r[2][16];
        #pragma unroll
        for (int i = 0; i < 2; ++i)
            #pragma unroll
            for (int h = 0; h < 4; ++h) {
                float4 v = *(float4*)&c2s[wm * 64 + i * 32 + 4 * q + 8 * h];
                c2r[i][h * 4 + 0] = v.x; c2r[i][h * 4 + 1] = v.y;
                c2r[i][h * 4 + 2] = v.z; c2r[i][h * 4 + 3] = v.w;
            }
        int ibase = code0 + wm * 64 + 4 * q;
        const f32x16* accp[2][2] = {{&acc00, &acc01}, {&acc10, &acc11}};
        #pragma unroll
        for (int j = 0; j < 2; ++j) {
            #pragma unroll
            for (int i = 0; i < 2; ++i) {
                const f32x16& a = *accp[i][j];
                #pragma unroll
                for (int r = 0; r < 16; ++r) {
                    float s = c2r[i][r] - 2.0f * a[r];
                    int idx = ibase + i * 32 + (r & 3) + 8 * (r >> 2);
                    if (s < rs1[j])      { rs2[j] = rs1[j]; ri2[j] = ri1[j]; rs1[j] = s; ri1[j] = idx; }
                    else if (s < rs2[j]) { rs2[j] = s; ri2[j] = idx; }
                }
            }
        }
    }
    // merge q-halves (lanes l <-> l^32)
    #pragma unroll
    for (int j = 0; j < 2; ++j) {
        float os1 = __shfl_xor(rs1[j], 32, 64);
        int   oi1 = __shfl_xor(ri1[j], 32, 64);
        float os2 = __shfl_xor(rs2[j], 32, 64);
        int   oi2 = __shfl_xor(ri2[j], 32, 64);
        if (os1 < rs1[j])      { rs2[j] = rs1[j]; ri2[j] = ri1[j]; rs1[j] = os1; ri1[j] = oi1; }
        else if (os1 < rs2[j]) { rs2[j] = os1; ri2[j] = oi1; }
        if (os2 < rs1[j])      { rs2[j] = rs1[j]; ri2[j] = ri1[j]; rs1[j] = os2; ri1[j] = oi2; }
        else if (os2 < rs2[j]) { rs2[j] = os2; ri2[j] = oi2; }
    }
    __syncthreads();
    if (q == 0) {
        #pragma unroll
        for (int j = 0; j < 2; ++j)
            mbuf[((wm * 2 + wn) * 2 + j) * 32 + l31] =
                make_float4(rs1[j], __int_as_float(ri1[j]), rs2[j], __int_as_float(ri2[j]));
    }
    __syncthreads();
    if (tid < 128) {
        int wn_ = tid >> 6, j_ = (tid >> 5) & 1, l5 = tid & 31;
        float4 e0 = mbuf[((0 * 2 + wn_) * 2 + j_) * 32 + l5];
        float4 e1 = mbuf[((1 * 2 + wn_) * 2 + j_) * 32 + l5];
        float bs1 = e0.x; int bi1 = __float_as_int(e0.y);
        float bs2 = e0.z; int bi2 = __float_as_int(e0.w);
        float cs[2] = {e1.x, e1.z};
        int   ci[2] = {__float_as_int(e1.y), __float_as_int(e1.w)};
        #pragma unroll
        for (int t = 0; t < 2; ++t) {
            if (cs[t] < bs1)      { bs2 = bs1; bi2 = bi1; bs1 = cs[t]; bi1 = ci[t]; }
            else if (cs[t] < bs2) { bs2 = cs[t]; bi2 = ci[t]; }
        }
        int n = r0 + tid;
        size_t o = ((size_t)split * N_ + n) * 2;
        t2s[o] = bs1; t2s[o + 1] = bs2;
        t2i[o] = bi1; t2i[o + 1] = bi2;
    }
}

// ---------------------------------------------------------------------------
// D: prefilter 16 candidates -> top-8 by scan score; fp64 rescore those 8;
//    gather z_q; loss partials; transposed (B,C,H,W) write.
__global__ __launch_bounds__(256) void k_finalize(
        const float* __restrict__ zf, const float* __restrict__ cb,
        const float* __restrict__ t2s, const int* __restrict__ t2i,
        float* __restrict__ out, float* __restrict__ partials) {
    __shared__ int    c8[16][8];
    __shared__ double sc[8];
    __shared__ int    li[8];
    __shared__ int    bidx[16];
    __shared__ float  wsum[4];
    __shared__ float  tile[16][260];
    int n0 = blockIdx.x * 16;
    int tid = threadIdx.x;

    // step 1: per-row top-8 prefilter by stored scan score
    if (tid < 16) {
        int n = n0 + tid;
        float s8[8]; int i8[8];
        #pragma unroll
        for (int t = 0; t < 8; ++t) { s8[t] = 1e30f; i8[t] = 0; }
        for (int t = 0; t < 2 * NSPLIT; ++t) {
            size_t o = ((size_t)(t >> 1) * N_ + n) * 2 + (t & 1);
            float s = t2s[o]; int ci = t2i[o];
            if (s < s8[7]) {
                int p = 7;
                while (p > 0 && s < s8[p - 1]) { s8[p] = s8[p - 1]; i8[p] = i8[p - 1]; --p; }
                s8[p] = s; i8[p] = ci;
            }
        }
        #pragma unroll
        for (int t = 0; t < 8; ++t) c8[tid][t] = i8[t];
    }
    __syncthreads();

    // step 2: fp64 rescore of 8 candidates (one 32-lane group each), rows serial
    int cand = tid >> 5, lane = tid & 31;
    for (int l = 0; l < 16; ++l) {
        int n = n0 + l;
        int ci = c8[l][cand];
        double acc = 0.0, ccs = 0.0;
        #pragma unroll
        for (int j = 0; j < 8; ++j) {
            int c = lane + 32 * j;
            double zc = (double)zf[(size_t)n * K_ + c];
            double bc = (double)cb[(size_t)ci * K_ + c];
            acc += zc * bc;
            ccs += bc * bc;
        }
        #pragma unroll
        for (int off = 16; off; off >>= 1) {
            acc += __shfl_down(acc, off, 32);
            ccs += __shfl_down(ccs, off, 32);
        }
        if (lane == 0) { sc[cand] = ccs - 2.0 * acc; li[cand] = ci; }
        __syncthreads();
        if (tid == 0) {
            double bs = sc[0]; int bi = li[0];
            for (int t = 1; t < 8; ++t)
                if (sc[t] < bs || (sc[t] == bs && li[t] < bi)) { bs = sc[t]; bi = li[t]; }
            bidx[l] = bi;
            out[(size_t)NZQ + 1 + n] = (float)bi;   // indices output
        }
        __syncthreads();
    }

    // phase 2: gather + squared-error partial + stage for transposed write
    float accl = 0.f;
    for (int l = 0; l < 16; ++l) {
        int n = n0 + l;
        int bi = bidx[l];
        float zq = cb[(size_t)bi * K_ + tid];
        float d  = zf[(size_t)n * K_ + tid] - zq;
        accl += d * d;
        tile[l][tid] = zq;
    }
    #pragma unroll
    for (int off = 32; off; off >>= 1) accl += __shfl_down(accl, off, 64);
    if ((tid & 63) == 0) wsum[tid >> 6] = accl;
    __syncthreads();
    if (tid == 0) partials[blockIdx.x] = wsum[0] + wsum[1] + wsum[2] + wsum[3];
    // transposed write: out[(b*C + c)*HW + hw0 + l]
    int b = n0 >> 10, hw0 = n0 & 1023;
    #pragma unroll
    for (int g = 0; g < 4; ++g) {
        float4 v = make_float4(tile[g * 4 + 0][tid], tile[g * 4 + 1][tid],
                               tile[g * 4 + 2][tid], tile[g * 4 + 3][tid]);
        *(float4*)&out[((size_t)b * C_ + tid) * HW_ + hw0 + g * 4] = v;
    }
}

// ---------------------------------------------------------------------------
// E: loss = 1.25 * sum(partials) / (N*C)
__global__ void k_loss(const float* __restrict__ partials, float* __restrict__ out) {
    __shared__ double ws4[4];
    int tid = threadIdx.x;
    double s = 0.0;
    for (int i = tid; i < 1024; i += 256) s += (double)partials[i];
    #pragma unroll
    for (int off = 32; off; off >>= 1) s += __shfl_down(s, off, 64);
    if ((tid & 63) == 0) ws4[tid >> 6] = s;
    __syncthreads();
    if (tid == 0) {
        double tot = ws4[0] + ws4[1] + ws4[2] + ws4[3];
        out[NZQ] = (float)(1.25 * tot / (double)NZQ);
    }
}

// ---------------------------------------------------------------------------
extern "C" void kernel_launch(void* const* d_in, const int* in_sizes, int n_in,
                              void* d_out, int out_size, void* d_ws, size_t ws_size,
                              hipStream_t stream) {
    const float* z  = (const float*)d_in[0];
    const float* fc = (const float*)d_in[1];
    const float* wt = (const float*)d_in[2];
    float* out = (float*)d_out;

    float* ws = (float*)d_ws;
    const size_t OFF_ZF   = 0;                                   // 4,194,304 f
    const size_t OFF_CB   = OFF_ZF + (size_t)N_ * K_;            // 2,097,152 f
    const size_t OFF_C2   = OFF_CB + (size_t)NE_ * K_;           // 8,192 f
    const size_t OFF_T2S  = OFF_C2 + NE_;                        // 262,144 f
    const size_t OFF_T2I  = OFF_T2S + (size_t)NSPLIT * N_ * 2;   // 262,144 i
    const size_t OFF_PART = OFF_T2I + (size_t)NSPLIT * N_ * 2;   // 1,024 f
    const size_t OFF_ZH   = OFF_PART + 1024;                     // fp16 N*K = 2,097,152 f
    const size_t OFF_CBH  = OFF_ZH + (size_t)N_ * K_ / 2;        // fp16 NE*K = 1,048,576 f

    float* zf   = ws + OFF_ZF;
    float* cb   = ws + OFF_CB;
    float* c2   = ws + OFF_C2;
    float* t2s  = ws + OFF_T2S;
    int*   t2i  = (int*)(ws + OFF_T2I);
    float* part = ws + OFF_PART;
    u16*   zh   = (u16*)(ws + OFF_ZH);
    u16*   cbh  = (u16*)(ws + OFF_CBH);

    k_transpose_z<<<dim3(HW_ / 32, C_ / 32, B_), dim3(32, 8), 0, stream>>>(z, zf, zh);
    k_codebook_gemm<<<dim3(NE_ / 64, K_ / 64), 256, 0, stream>>>(fc, wt, cb, cbh);
    k_c2<<<NE_ / 4, 256, 0, stream>>>(cb, c2);
    k_scan_mfma<<<dim3(N_ / 128, NSPLIT), 256, 0, stream>>>(zh, cbh, c2, t2s, t2i);
    k_finalize<<<N_ / 16, 256, 0, stream>>>(zf, cb, t2s, t2i, out, part);
    k_loss<<<1, 256, 0, stream>>>(part, out);
}